// Round 4
// baseline (211.551 us; speedup 1.0000x reference)
//
#include <hip/hip_runtime.h>

#define D_    2560
#define NH_   8
#define NKV_  4
#define HD_   256
#define FFN_  10240
#define QD_   2048
#define CTX_  4096
#define EPSF  1e-6f
#define LCHUNKS 16
#define LCHUNK  256

__device__ __forceinline__ float wave_red_sum(float v) {
#pragma unroll
    for (int o = 32; o > 0; o >>= 1) v += __shfl_down(v, o, 64);
    return v;
}

__device__ __forceinline__ float block_red_sum(float v) {
    __shared__ float s[4];
    __shared__ float tot;
    int lane = threadIdx.x & 63, w = threadIdx.x >> 6;
    v = wave_red_sum(v);
    if (lane == 0) s[w] = v;
    __syncthreads();
    if (threadIdx.x == 0) tot = s[0] + s[1] + s[2] + s[3];
    __syncthreads();
    return tot;
}

__device__ __forceinline__ float block_red_max(float v) {
    __shared__ float s[4];
    __shared__ float tot;
    int lane = threadIdx.x & 63, w = threadIdx.x >> 6;
#pragma unroll
    for (int o = 32; o > 0; o >>= 1) v = fmaxf(v, __shfl_down(v, o, 64));
    if (lane == 0) s[w] = v;
    __syncthreads();
    if (threadIdx.x == 0) tot = fmaxf(fmaxf(s[0], s[1]), fmaxf(s[2], s[3]));
    __syncthreads();
    return tot;
}

// ---- streaming GEMV partials (kept for small Wq/Wo) ----
template <int SLOTS>
__global__ __launch_bounds__(256) void k_stream(const float* __restrict__ W,
                                                const float* __restrict__ x,
                                                float* __restrict__ part,
                                                int total) {
    const float4* W4 = (const float4*)W;
    const float4* X4 = (const float4*)x;
    int lane = threadIdx.x & 63;
    int gw = (blockIdx.x * 256 + threadIdx.x) >> 6;
    int nw = (gridDim.x * 256) >> 6;
#pragma unroll 4
    for (int it = gw; it < total; it += nw) {
        int slot = it % SLOTS;
        float4 w = W4[(size_t)it * 64 + lane];
        float4 xx = X4[slot * 64 + lane];
        float p = w.x * xx.x + w.y * xx.y + w.z * xx.z + w.w * xx.w;
        p = wave_red_sum(p);
        if (lane == 0) part[it] = p;
    }
}

// ---- deep-ILP fused GeGLU GEMV: persistent waves, x in registers,
// 5-deep independent weight loads, gelu fused, writes gu directly ----
__global__ __launch_bounds__(256) void k_geglu_deep(const float* __restrict__ Wg,
                                                    const float* __restrict__ Wu,
                                                    const float* __restrict__ h,
                                                    float* __restrict__ gu) {
    int lane = threadIdx.x & 63;
    int gw = (blockIdx.x * 256 + threadIdx.x) >> 6;
    int nw = (gridDim.x * 256) >> 6;
    const float4* X = (const float4*)h;
    float4 xr[10];
#pragma unroll
    for (int k = 0; k < 10; k++) xr[k] = X[lane + k * 64];
    for (int r = gw; r < FFN_; r += nw) {
        const float4* G = (const float4*)Wg + (size_t)r * 640 + lane;
        const float4* U = (const float4*)Wu + (size_t)r * 640 + lane;
        float4 b[5];
        float ag = 0.f, au = 0.f;
#pragma unroll
        for (int k = 0; k < 5; k++) b[k] = G[k * 64];
#pragma unroll
        for (int k = 0; k < 5; k++)
            ag += b[k].x * xr[k].x + b[k].y * xr[k].y + b[k].z * xr[k].z + b[k].w * xr[k].w;
#pragma unroll
        for (int k = 0; k < 5; k++) b[k] = G[(k + 5) * 64];
#pragma unroll
        for (int k = 0; k < 5; k++)
            ag += b[k].x * xr[k + 5].x + b[k].y * xr[k + 5].y + b[k].z * xr[k + 5].z + b[k].w * xr[k + 5].w;
#pragma unroll
        for (int k = 0; k < 5; k++) b[k] = U[k * 64];
#pragma unroll
        for (int k = 0; k < 5; k++)
            au += b[k].x * xr[k].x + b[k].y * xr[k].y + b[k].z * xr[k].z + b[k].w * xr[k].w;
#pragma unroll
        for (int k = 0; k < 5; k++) b[k] = U[(k + 5) * 64];
#pragma unroll
        for (int k = 0; k < 5; k++)
            au += b[k].x * xr[k + 5].x + b[k].y * xr[k + 5].y + b[k].z * xr[k + 5].z + b[k].w * xr[k + 5].w;
#pragma unroll
        for (int o = 32; o > 0; o >>= 1) {
            ag += __shfl_down(ag, o, 64);
            au += __shfl_down(au, o, 64);
        }
        if (lane == 0) {
            float g = ag;
            float t = tanhf(0.7978845608028654f * (g + 0.044715f * g * g * g));
            gu[r] = 0.5f * g * (1.f + t) * au;
        }
    }
}

// ---- Wd partials: 4-deep chunk groups.  item = row*10 + seg ----
__global__ __launch_bounds__(256) void k_wd(const float* __restrict__ Wd,
                                            const float* __restrict__ gu,
                                            float* __restrict__ part) {
    int lane = threadIdx.x & 63;
    int gw = (blockIdx.x * 256 + threadIdx.x) >> 6;
    int nw = (gridDim.x * 256) >> 6;
    const float4* X = (const float4*)gu;
    for (int it = gw; it < D_ * 10; it += nw) {
        int row = it / 10, seg = it - row * 10;
        const float4* Wr = (const float4*)Wd + (size_t)row * 2560 + seg * 256 + lane;
        const float4* xp = X + seg * 256 + lane;
        float4 w0 = Wr[0], w1 = Wr[64], w2 = Wr[128], w3 = Wr[192];
        float4 x0 = xp[0], x1 = xp[64], x2 = xp[128], x3 = xp[192];
        float p = w0.x * x0.x + w0.y * x0.y + w0.z * x0.z + w0.w * x0.w
                + w1.x * x1.x + w1.y * x1.y + w1.z * x1.z + w1.w * x1.w
                + w2.x * x2.x + w2.y * x2.y + w2.z * x2.z + w2.w * x2.w
                + w3.x * x3.x + w3.y * x3.y + w3.z * x3.z + w3.w * x3.w;
        p = wave_red_sum(p);
        if (lane == 0) part[it] = p;
    }
}

// ---- pure-read roofline probe over Wg (105 MB): 8 loads in flight/lane ----
__global__ __launch_bounds__(256) void k_probe(const float4* __restrict__ W,
                                               float* __restrict__ sink) {
    size_t t = (size_t)blockIdx.x * 256 + threadIdx.x;
    float4 v[8];
#pragma unroll
    for (int k = 0; k < 8; k++) v[k] = W[t + (size_t)k * 819200];
    float a = 0.f;
#pragma unroll
    for (int k = 0; k < 8; k++) a += v[k].x + v[k].y + v[k].z + v[k].w;
    a = wave_red_sum(a);
    if ((threadIdx.x & 63) == 0) sink[((size_t)blockIdx.x * 256 + threadIdx.x) >> 6] = a;
}

// out1 = (res?) res + rms(a)*(1+w1);  a[i] = sum_{s<slots} apart[i*slots+s]
__global__ void k_res_rms(const float* __restrict__ res,
                          const float* __restrict__ apart, int slots,
                          const float* __restrict__ w1, float* __restrict__ out1,
                          const float* __restrict__ w2, float* __restrict__ out2) {
    const int K = D_ / 256;
    int t = threadIdx.x;
    float va[K];
    float ss = 0.f;
#pragma unroll
    for (int k = 0; k < K; k++) {
        int i = t + k * 256;
        float v = 0.f;
        for (int s = 0; s < slots; s++) v += apart[(size_t)i * slots + s];
        va[k] = v;
        ss += v * v;
    }
    float tot = block_red_sum(ss);
    float rs = rsqrtf(tot / (float)D_ + EPSF);
    float vo[K];
    float ss2 = 0.f;
#pragma unroll
    for (int k = 0; k < K; k++) {
        int i = t + k * 256;
        float r = res ? res[i] : 0.f;
        vo[k] = r + va[k] * rs * (1.f + w1[i]);
        out1[i] = vo[k];
        ss2 += vo[k] * vo[k];
    }
    if (out2) {
        float tot2 = block_red_sum(ss2);
        float rs2 = rsqrtf(tot2 / (float)D_ + EPSF);
#pragma unroll
        for (int k = 0; k < K; k++) {
            int i = t + k * 256;
            out2[i] = vo[k] * rs2 * (1.f + w2[i]);
        }
    }
}

__global__ void k_qnorm_rope(const float* __restrict__ part_q,
                             const float* __restrict__ cosv,
                             const float* __restrict__ sinv,
                             float* __restrict__ qout) {
    __shared__ float qn[HD_];
    int h = blockIdx.x, d = threadIdx.x;
    int r = h * HD_ + d;
    float v = 0.f;
#pragma unroll
    for (int s = 0; s < 10; s++) v += part_q[(size_t)r * 10 + s];
    float tot = block_red_sum(v * v);
    float rs = rsqrtf(tot / (float)HD_ + EPSF);
    float n = v * rs;
    qn[d] = n;
    __syncthreads();
    float rot = (d < HD_ / 2) ? -qn[d + HD_ / 2] : qn[d - HD_ / 2];
    qout[h * HD_ + d] = n * cosv[d] + rot * sinv[d];
}

__global__ void k_scores(const float* __restrict__ Kc, const float* __restrict__ q,
                         const float* __restrict__ mask, float* __restrict__ s) {
    int kvh = blockIdx.x, chunk = blockIdx.y;
    int lane = threadIdx.x & 63, w = threadIdx.x >> 6;
    int h0 = 2 * kvh, h1 = h0 + 1;
    const float4* q4 = (const float4*)q;
    float4 q0 = q4[h0 * 64 + lane];
    float4 q1 = q4[h1 * 64 + lane];
    int lbase = chunk * LCHUNK + w * 64;
    for (int i = 0; i < 64; i++) {
        int l = lbase + i;
        const float4* Kr = (const float4*)(Kc + ((size_t)kvh * CTX_ + l) * HD_);
        float4 kk = Kr[lane];
        float d0 = kk.x * q0.x + kk.y * q0.y + kk.z * q0.z + kk.w * q0.w;
        float d1 = kk.x * q1.x + kk.y * q1.y + kk.z * q1.z + kk.w * q1.w;
#pragma unroll
        for (int o = 32; o > 0; o >>= 1) {
            d0 += __shfl_down(d0, o, 64);
            d1 += __shfl_down(d1, o, 64);
        }
        if (lane == 0) {
            float m = mask[l];
            s[(size_t)h0 * CTX_ + l] = d0 + m;
            s[(size_t)h1 * CTX_ + l] = d1 + m;
        }
    }
}

__global__ void k_softmax(float* __restrict__ s) {
    int h = blockIdx.x, t = threadIdx.x;
    float* sh = s + (size_t)h * CTX_;
    float m = -1e30f;
    for (int l = t; l < CTX_; l += 256) m = fmaxf(m, sh[l]);
    m = block_red_max(m);
    float sum = 0.f;
    for (int l = t; l < CTX_; l += 256) {
        float e = expf(sh[l] - m);
        sh[l] = e;
        sum += e;
    }
    sum = block_red_sum(sum);
    float inv = 1.f / sum;
    for (int l = t; l < CTX_; l += 256) sh[l] *= inv;
}

__global__ void k_wv(const float* __restrict__ V, const float* __restrict__ p,
                     float* __restrict__ part) {
    int kvh = blockIdx.x, chunk = blockIdx.y, d = threadIdx.x;
    int h0 = 2 * kvh, h1 = h0 + 1;
    __shared__ float p0[LCHUNK], p1[LCHUNK];
    int l0 = chunk * LCHUNK;
    p0[d] = p[(size_t)h0 * CTX_ + l0 + d];
    p1[d] = p[(size_t)h1 * CTX_ + l0 + d];
    __syncthreads();
    const float* Vb = V + ((size_t)kvh * CTX_ + l0) * HD_;
    float a0 = 0.f, a1 = 0.f;
    for (int li = 0; li < LCHUNK; li++) {
        float v = Vb[(size_t)li * HD_ + d];
        a0 += p0[li] * v;
        a1 += p1[li] * v;
    }
    part[((h0 * LCHUNKS) + chunk) * HD_ + d] = a0;
    part[((h1 * LCHUNKS) + chunk) * HD_ + d] = a1;
}

__global__ void k_reduce_a(const float* __restrict__ part, float* __restrict__ a) {
    int h = blockIdx.x, d = threadIdx.x;
    float s = 0.f;
#pragma unroll
    for (int c = 0; c < LCHUNKS; c++) s += part[((h * LCHUNKS) + c) * HD_ + d];
    a[h * HD_ + d] = s;
}

// ffn[r] = sum of 10 Wd partials.  grid=D_/256
__global__ void k_reduce_ffn(const float* __restrict__ part_d, float* __restrict__ ffn) {
    int r = blockIdx.x * 256 + threadIdx.x;
    float s = 0.f;
#pragma unroll
    for (int k = 0; k < 10; k++) s += part_d[(size_t)r * 10 + k];
    ffn[r] = s;
}

extern "C" void kernel_launch(void* const* d_in, const int* in_sizes, int n_in,
                              void* d_out, int out_size, void* d_ws, size_t ws_size,
                              hipStream_t stream) {
    const float* x     = (const float*)d_in[0];
    const float* cosv  = (const float*)d_in[1];
    const float* sinv  = (const float*)d_in[2];
    const float* mask  = (const float*)d_in[3];
    const float* cK    = (const float*)d_in[4];
    const float* cV    = (const float*)d_in[5];
    const float* w_in  = (const float*)d_in[7];
    const float* w_pa  = (const float*)d_in[8];
    const float* w_pf  = (const float*)d_in[9];
    const float* w_pff = (const float*)d_in[10];
    const float* Wq    = (const float*)d_in[11];
    const float* Wo    = (const float*)d_in[12];
    const float* Wg    = (const float*)d_in[13];
    const float* Wu    = (const float*)d_in[14];
    const float* Wd    = (const float*)d_in[15];

    float* ws    = (float*)d_ws;
    float* h     = ws;            // 2560
    float* q     = ws + 2560;     // 2048
    float* sc    = ws + 4608;     // 32768
    float* pwv   = ws + 37376;    // 32768
    float* a     = ws + 70144;    // 2048
    float* x2    = ws + 72192;    // 2560
    float* h2    = ws + 74752;    // 2560
    float* gu    = ws + 77312;    // 10240
    float* ffn   = ws + 87552;    // 2560
    float* A     = ws + 90112;
    float* partq = A;             // 20480 (QD*10, dead after qnorm_rope)
    float* parto = A;             // 20480 (D*8, dead after res_rms #2)
    float* partd = A;             // 25600 (D*10)
    float* sink  = A + 25600;     // 12800 (probe)
    float* out   = (float*)d_out;

    const int SB = 2048;

    // h = rmsnorm(x, w_in)
    k_res_rms<<<1, 256, 0, stream>>>(nullptr, x, 1, w_in, h, nullptr, nullptr);
    // qraw partials = h @ Wq.T
    k_stream<10><<<SB, 256, 0, stream>>>(Wq, h, partq, QD_ * 10);
    k_qnorm_rope<<<NH_, HD_, 0, stream>>>(partq, cosv, sinv, q);
    // attention
    k_scores<<<dim3(NKV_, LCHUNKS), 256, 0, stream>>>(cK, q, mask, sc);
    k_softmax<<<NH_, 256, 0, stream>>>(sc);
    k_wv<<<dim3(NKV_, LCHUNKS), HD_, 0, stream>>>(cV, sc, pwv);
    k_reduce_a<<<NH_, HD_, 0, stream>>>(pwv, a);
    // ao partials = a @ Wo.T
    k_stream<8><<<SB, 256, 0, stream>>>(Wo, a, parto, D_ * 8);
    k_res_rms<<<1, 256, 0, stream>>>(x, parto, 8, w_pa, x2, w_pf, h2);
    // gu = gelu(h2@Wg.T) * (h2@Wu.T)   — fused, deep-ILP
    k_geglu_deep<<<1280, 256, 0, stream>>>(Wg, Wu, h2, gu);
    // ffn partials = gu @ Wd.T (10 segs/row), then reduce
    k_wd<<<SB, 256, 0, stream>>>(Wd, gu, partd);
    k_reduce_ffn<<<D_ / 256, 256, 0, stream>>>(partd, ffn);
    // out = x2 + rms(ffn)*(1+w_pff)
    k_res_rms<<<1, 256, 0, stream>>>(x2, ffn, 1, w_pff, out, nullptr, nullptr);
    // roofline witness: pure 105 MB read, 8-deep, no per-iter reduce
    k_probe<<<3200, 256, 0, stream>>>((const float4*)Wg, sink);
}

// Round 6
// 185.170 us; speedup vs baseline: 1.1425x; 1.1425x over previous
//
#include <hip/hip_runtime.h>

#define D_    2560
#define NH_   8
#define NKV_  4
#define HD_   256
#define FFN_  10240
#define QD_   2048
#define CTX_  4096
#define EPSF  1e-6f
#define LCHUNKS 16
#define LCHUNK  256

typedef float f4 __attribute__((ext_vector_type(4)));

__device__ __forceinline__ float wave_red_sum(float v) {
#pragma unroll
    for (int o = 32; o > 0; o >>= 1) v += __shfl_down(v, o, 64);
    return v;
}

__device__ __forceinline__ float block_red_sum(float v) {
    __shared__ float s[4];
    __shared__ float tot;
    int lane = threadIdx.x & 63, w = threadIdx.x >> 6;
    v = wave_red_sum(v);
    if (lane == 0) s[w] = v;
    __syncthreads();
    if (threadIdx.x == 0) tot = s[0] + s[1] + s[2] + s[3];
    __syncthreads();
    return tot;
}

__device__ __forceinline__ float block_red_max(float v) {
    __shared__ float s[4];
    __shared__ float tot;
    int lane = threadIdx.x & 63, w = threadIdx.x >> 6;
#pragma unroll
    for (int o = 32; o > 0; o >>= 1) v = fmaxf(v, __shfl_down(v, o, 64));
    if (lane == 0) s[w] = v;
    __syncthreads();
    if (threadIdx.x == 0) tot = fmaxf(fmaxf(s[0], s[1]), fmaxf(s[2], s[3]));
    __syncthreads();
    return tot;
}

// ---- GEMV, nontemporal weight stream, x staged in LDS, wave per row ----
template <int COLS>
__global__ __launch_bounds__(256) void k_gemv_nt(const float* __restrict__ W,
                                                 const float* __restrict__ x,
                                                 float* __restrict__ y) {
    constexpr int NC = COLS / 4;
    constexpr int CPL = NC / 64;
    __shared__ f4 xs[NC];
    int t = threadIdx.x;
    for (int i = t; i < NC; i += 256) xs[i] = ((const f4*)x)[i];
    __syncthreads();
    int lane = t & 63;
    int row = blockIdx.x * 4 + (t >> 6);
    const f4* Wr = (const f4*)W + (size_t)row * NC + lane;
    f4 wv[CPL];
#pragma unroll
    for (int k = 0; k < CPL; k++) wv[k] = __builtin_nontemporal_load(Wr + k * 64);
    float acc = 0.f;
#pragma unroll
    for (int k = 0; k < CPL; k++) {
        f4 xx = xs[lane + k * 64];
        acc += wv[k].x * xx.x + wv[k].y * xx.y + wv[k].z * xx.z + wv[k].w * xx.w;
    }
    acc = wave_red_sum(acc);
    if (lane == 0) y[row] = acc;
}

// ---- fused GeGLU: 20 nontemporal loads in flight per wave ----
__global__ __launch_bounds__(256) void k_geglu_nt(const float* __restrict__ Wg,
                                                  const float* __restrict__ Wu,
                                                  const float* __restrict__ h,
                                                  float* __restrict__ gu) {
    __shared__ f4 xs[640];   // 10 KB
    int t = threadIdx.x;
    for (int i = t; i < 640; i += 256) xs[i] = ((const f4*)h)[i];
    __syncthreads();
    int lane = t & 63;
    int row = blockIdx.x * 4 + (t >> 6);
    const f4* G = (const f4*)Wg + (size_t)row * 640 + lane;
    const f4* U = (const f4*)Wu + (size_t)row * 640 + lane;
    f4 wg[10], wu[10];
#pragma unroll
    for (int k = 0; k < 10; k++) wg[k] = __builtin_nontemporal_load(G + k * 64);
#pragma unroll
    for (int k = 0; k < 10; k++) wu[k] = __builtin_nontemporal_load(U + k * 64);
    float ag = 0.f, au = 0.f;
#pragma unroll
    for (int k = 0; k < 10; k++) {
        f4 xx = xs[lane + k * 64];
        ag += wg[k].x * xx.x + wg[k].y * xx.y + wg[k].z * xx.z + wg[k].w * xx.w;
        au += wu[k].x * xx.x + wu[k].y * xx.y + wu[k].z * xx.z + wu[k].w * xx.w;
    }
#pragma unroll
    for (int o = 32; o > 0; o >>= 1) {
        ag += __shfl_down(ag, o, 64);
        au += __shfl_down(au, o, 64);
    }
    if (lane == 0) {
        float g = ag;
        float tt = tanhf(0.7978845608028654f * (g + 0.044715f * g * g * g));
        gu[row] = 0.5f * g * (1.f + tt) * au;
    }
}

// ---- Wd: wave per row over FULL 10240-col row (40 chunks/lane, 4 groups
// of 10 back-to-back nt loads), gu staged in 40 KB LDS ----
__global__ __launch_bounds__(256) void k_wd_nt(const float* __restrict__ Wd,
                                               const float* __restrict__ gu,
                                               float* __restrict__ ffn) {
    __shared__ f4 xs[2560];  // 40 KB
    int t = threadIdx.x;
    for (int i = t; i < 2560; i += 256) xs[i] = ((const f4*)gu)[i];
    __syncthreads();
    int lane = t & 63;
    int row = blockIdx.x * 4 + (t >> 6);
    const f4* Wr = (const f4*)Wd + (size_t)row * 2560 + lane;
    float acc = 0.f;
#pragma unroll
    for (int g = 0; g < 4; g++) {
        f4 wv[10];
#pragma unroll
        for (int k = 0; k < 10; k++)
            wv[k] = __builtin_nontemporal_load(Wr + (g * 10 + k) * 64);
#pragma unroll
        for (int k = 0; k < 10; k++) {
            f4 xx = xs[lane + (g * 10 + k) * 64];
            acc += wv[k].x * xx.x + wv[k].y * xx.y + wv[k].z * xx.z + wv[k].w * xx.w;
        }
    }
    acc = wave_red_sum(acc);
    if (lane == 0) ffn[row] = acc;
}

// ---- pure-read roofline probe over Wg (105 MB): 8 loads in flight/lane ----
__global__ __launch_bounds__(256) void k_probe(const f4* __restrict__ W,
                                               float* __restrict__ sink) {
    size_t t = (size_t)blockIdx.x * 256 + threadIdx.x;
    f4 v[8];
#pragma unroll
    for (int k = 0; k < 8; k++) v[k] = W[t + (size_t)k * 819200];
    float a = 0.f;
#pragma unroll
    for (int k = 0; k < 8; k++) a += v[k].x + v[k].y + v[k].z + v[k].w;
    a = wave_red_sum(a);
    if ((threadIdx.x & 63) == 0) sink[((size_t)blockIdx.x * 256 + threadIdx.x) >> 6] = a;
}

// out1 = (res?) res + rms(a)*(1+w1);  optionally out2 = rms(out1)*(1+w2)
__global__ void k_res_rms(const float* __restrict__ res,
                          const float* __restrict__ a,
                          const float* __restrict__ w1, float* __restrict__ out1,
                          const float* __restrict__ w2, float* __restrict__ out2) {
    const int K = D_ / 256;
    int t = threadIdx.x;
    float va[K];
    float ss = 0.f;
#pragma unroll
    for (int k = 0; k < K; k++) {
        int i = t + k * 256;
        va[k] = a[i];
        ss += va[k] * va[k];
    }
    float tot = block_red_sum(ss);
    float rs = rsqrtf(tot / (float)D_ + EPSF);
    float vo[K];
    float ss2 = 0.f;
#pragma unroll
    for (int k = 0; k < K; k++) {
        int i = t + k * 256;
        float r = res ? res[i] : 0.f;
        vo[k] = r + va[k] * rs * (1.f + w1[i]);
        out1[i] = vo[k];
        ss2 += vo[k] * vo[k];
    }
    if (out2) {
        float tot2 = block_red_sum(ss2);
        float rs2 = rsqrtf(tot2 / (float)D_ + EPSF);
#pragma unroll
        for (int k = 0; k < K; k++) {
            int i = t + k * 256;
            out2[i] = vo[k] * rs2 * (1.f + w2[i]);
        }
    }
}

__global__ void k_qnorm_rope(const float* __restrict__ qraw,
                             const float* __restrict__ cosv,
                             const float* __restrict__ sinv,
                             float* __restrict__ qout) {
    __shared__ float qn[HD_];
    int h = blockIdx.x, d = threadIdx.x;
    float v = qraw[h * HD_ + d];
    float tot = block_red_sum(v * v);
    float rs = rsqrtf(tot / (float)HD_ + EPSF);
    float n = v * rs;
    qn[d] = n;
    __syncthreads();
    float rot = (d < HD_ / 2) ? -qn[d + HD_ / 2] : qn[d - HD_ / 2];
    qout[h * HD_ + d] = n * cosv[d] + rot * sinv[d];
}

__global__ void k_scores(const float* __restrict__ Kc, const float* __restrict__ q,
                         const float* __restrict__ mask, float* __restrict__ s) {
    int kvh = blockIdx.x, chunk = blockIdx.y;
    int lane = threadIdx.x & 63, w = threadIdx.x >> 6;
    int h0 = 2 * kvh, h1 = h0 + 1;
    const f4* q4 = (const f4*)q;
    f4 q0 = q4[h0 * 64 + lane];
    f4 q1 = q4[h1 * 64 + lane];
    int lbase = chunk * LCHUNK + w * 64;
    for (int i = 0; i < 64; i++) {
        int l = lbase + i;
        const f4* Kr = (const f4*)(Kc + ((size_t)kvh * CTX_ + l) * HD_);
        f4 kk = __builtin_nontemporal_load(Kr + lane);
        float d0 = kk.x * q0.x + kk.y * q0.y + kk.z * q0.z + kk.w * q0.w;
        float d1 = kk.x * q1.x + kk.y * q1.y + kk.z * q1.z + kk.w * q1.w;
#pragma unroll
        for (int o = 32; o > 0; o >>= 1) {
            d0 += __shfl_down(d0, o, 64);
            d1 += __shfl_down(d1, o, 64);
        }
        if (lane == 0) {
            float m = mask[l];
            s[(size_t)h0 * CTX_ + l] = d0 + m;
            s[(size_t)h1 * CTX_ + l] = d1 + m;
        }
    }
}

__global__ void k_softmax(float* __restrict__ s) {
    int h = blockIdx.x, t = threadIdx.x;
    float* sh = s + (size_t)h * CTX_;
    float m = -1e30f;
    for (int l = t; l < CTX_; l += 256) m = fmaxf(m, sh[l]);
    m = block_red_max(m);
    float sum = 0.f;
    for (int l = t; l < CTX_; l += 256) {
        float e = expf(sh[l] - m);
        sh[l] = e;
        sum += e;
    }
    sum = block_red_sum(sum);
    float inv = 1.f / sum;
    for (int l = t; l < CTX_; l += 256) sh[l] *= inv;
}

__global__ void k_wv(const float* __restrict__ V, const float* __restrict__ p,
                     float* __restrict__ part) {
    int kvh = blockIdx.x, chunk = blockIdx.y, d = threadIdx.x;
    int h0 = 2 * kvh, h1 = h0 + 1;
    __shared__ float p0[LCHUNK], p1[LCHUNK];
    int l0 = chunk * LCHUNK;
    p0[d] = p[(size_t)h0 * CTX_ + l0 + d];
    p1[d] = p[(size_t)h1 * CTX_ + l0 + d];
    __syncthreads();
    const float* Vb = V + ((size_t)kvh * CTX_ + l0) * HD_;
    float a0 = 0.f, a1 = 0.f;
    for (int li = 0; li < LCHUNK; li++) {
        float v = Vb[(size_t)li * HD_ + d];
        a0 += p0[li] * v;
        a1 += p1[li] * v;
    }
    part[((h0 * LCHUNKS) + chunk) * HD_ + d] = a0;
    part[((h1 * LCHUNKS) + chunk) * HD_ + d] = a1;
}

__global__ void k_reduce_a(const float* __restrict__ part, float* __restrict__ a) {
    int h = blockIdx.x, d = threadIdx.x;
    float s = 0.f;
#pragma unroll
    for (int c = 0; c < LCHUNKS; c++) s += part[((h * LCHUNKS) + c) * HD_ + d];
    a[h * HD_ + d] = s;
}

extern "C" void kernel_launch(void* const* d_in, const int* in_sizes, int n_in,
                              void* d_out, int out_size, void* d_ws, size_t ws_size,
                              hipStream_t stream) {
    const float* x     = (const float*)d_in[0];
    const float* cosv  = (const float*)d_in[1];
    const float* sinv  = (const float*)d_in[2];
    const float* mask  = (const float*)d_in[3];
    const float* cK    = (const float*)d_in[4];
    const float* cV    = (const float*)d_in[5];
    const float* w_in  = (const float*)d_in[7];
    const float* w_pa  = (const float*)d_in[8];
    const float* w_pf  = (const float*)d_in[9];
    const float* w_pff = (const float*)d_in[10];
    const float* Wq    = (const float*)d_in[11];
    const float* Wo    = (const float*)d_in[12];
    const float* Wg    = (const float*)d_in[13];
    const float* Wu    = (const float*)d_in[14];
    const float* Wd    = (const float*)d_in[15];

    float* ws   = (float*)d_ws;
    float* h    = ws;            // 2560
    float* qraw = ws + 2560;     // 2048
    float* q    = ws + 4608;     // 2048
    float* sc   = ws + 6656;     // 32768
    float* pwv  = ws + 39424;    // 32768
    float* a    = ws + 72192;    // 2048
    float* ao   = ws + 74240;    // 2560
    float* x2   = ws + 76800;    // 2560
    float* h2   = ws + 79360;    // 2560
    float* gu   = ws + 81920;    // 10240
    float* ffn  = ws + 92160;    // 2560
    float* sink = ws + 94720;    // 12800
    float* out  = (float*)d_out;

    // h = rmsnorm(x, w_in)
    k_res_rms<<<1, 256, 0, stream>>>(nullptr, x, w_in, h, nullptr, nullptr);
    // qraw = h @ Wq.T
    k_gemv_nt<D_><<<QD_ / 4, 256, 0, stream>>>(Wq, h, qraw);
    k_qnorm_rope<<<NH_, HD_, 0, stream>>>(qraw, cosv, sinv, q);
    // attention
    k_scores<<<dim3(NKV_, LCHUNKS), 256, 0, stream>>>(cK, q, mask, sc);
    k_softmax<<<NH_, 256, 0, stream>>>(sc);
    k_wv<<<dim3(NKV_, LCHUNKS), HD_, 0, stream>>>(cV, sc, pwv);
    k_reduce_a<<<NH_, HD_, 0, stream>>>(pwv, a);
    // ao = a @ Wo.T
    k_gemv_nt<QD_><<<D_ / 4, 256, 0, stream>>>(Wo, a, ao);
    k_res_rms<<<1, 256, 0, stream>>>(x, ao, w_pa, x2, w_pf, h2);
    // gu = gelu(h2@Wg.T) * (h2@Wu.T)
    k_geglu_nt<<<FFN_ / 4, 256, 0, stream>>>(Wg, Wu, h2, gu);
    // ffn = gu @ Wd.T
    k_wd_nt<<<D_ / 4, 256, 0, stream>>>(Wd, gu, ffn);
    // out = x2 + rms(ffn)*(1+w_pff)
    k_res_rms<<<1, 256, 0, stream>>>(x2, ffn, w_pff, out, nullptr, nullptr);
    // roofline witness
    k_probe<<<3200, 256, 0, stream>>>((const f4*)Wg, sink);
}

// Round 7
// 106.461 us; speedup vs baseline: 1.9871x; 1.7393x over previous
//
#include <hip/hip_runtime.h>

#define D_    2560
#define NH_   8
#define NKV_  4
#define HD_   256
#define FFN_  10240
#define QD_   2048
#define CTX_  4096
#define EPSF  1e-6f
#define SCH   128   // score chunks: 512 blocks, 32 rows/block
#define WCH   64    // wv chunks: 256 blocks, 64 rows/block

typedef float f4 __attribute__((ext_vector_type(4)));

__device__ __forceinline__ float wave_red_sum(float v) {
#pragma unroll
    for (int o = 32; o > 0; o >>= 1) v += __shfl_down(v, o, 64);
    return v;
}

__device__ __forceinline__ float block_red_sum(float v) {
    __shared__ float s[4];
    __shared__ float tot;
    int lane = threadIdx.x & 63, w = threadIdx.x >> 6;
    v = wave_red_sum(v);
    if (lane == 0) s[w] = v;
    __syncthreads();
    if (threadIdx.x == 0) tot = s[0] + s[1] + s[2] + s[3];
    __syncthreads();
    return tot;
}

__device__ __forceinline__ float block_red_max(float v) {
    __shared__ float s[4];
    __shared__ float tot;
    int lane = threadIdx.x & 63, w = threadIdx.x >> 6;
#pragma unroll
    for (int o = 32; o > 0; o >>= 1) v = fmaxf(v, __shfl_down(v, o, 64));
    if (lane == 0) s[w] = v;
    __syncthreads();
    if (threadIdx.x == 0) tot = fmaxf(fmaxf(s[0], s[1]), fmaxf(s[2], s[3]));
    __syncthreads();
    return tot;
}

// ---- GEMV, nontemporal weight stream, x staged in LDS, wave per row ----
template <int COLS>
__global__ __launch_bounds__(256) void k_gemv_nt(const float* __restrict__ W,
                                                 const float* __restrict__ x,
                                                 float* __restrict__ y) {
    constexpr int NC = COLS / 4;
    constexpr int CPL = NC / 64;
    __shared__ f4 xs[NC];
    int t = threadIdx.x;
    for (int i = t; i < NC; i += 256) xs[i] = ((const f4*)x)[i];
    __syncthreads();
    int lane = t & 63;
    int row = blockIdx.x * 4 + (t >> 6);
    const f4* Wr = (const f4*)W + (size_t)row * NC + lane;
    f4 wv[CPL];
#pragma unroll
    for (int k = 0; k < CPL; k++) wv[k] = __builtin_nontemporal_load(Wr + k * 64);
    float acc = 0.f;
#pragma unroll
    for (int k = 0; k < CPL; k++) {
        f4 xx = xs[lane + k * 64];
        acc += wv[k].x * xx.x + wv[k].y * xx.y + wv[k].z * xx.z + wv[k].w * xx.w;
    }
    acc = wave_red_sum(acc);
    if (lane == 0) y[row] = acc;
}

// ---- fused GeGLU: 20 nontemporal loads in flight per wave ----
__global__ __launch_bounds__(256) void k_geglu_nt(const float* __restrict__ Wg,
                                                  const float* __restrict__ Wu,
                                                  const float* __restrict__ h,
                                                  float* __restrict__ gu) {
    __shared__ f4 xs[640];   // 10 KB
    int t = threadIdx.x;
    for (int i = t; i < 640; i += 256) xs[i] = ((const f4*)h)[i];
    __syncthreads();
    int lane = t & 63;
    int row = blockIdx.x * 4 + (t >> 6);
    const f4* G = (const f4*)Wg + (size_t)row * 640 + lane;
    const f4* U = (const f4*)Wu + (size_t)row * 640 + lane;
    f4 wg[10], wu[10];
#pragma unroll
    for (int k = 0; k < 10; k++) wg[k] = __builtin_nontemporal_load(G + k * 64);
#pragma unroll
    for (int k = 0; k < 10; k++) wu[k] = __builtin_nontemporal_load(U + k * 64);
    float ag = 0.f, au = 0.f;
#pragma unroll
    for (int k = 0; k < 10; k++) {
        f4 xx = xs[lane + k * 64];
        ag += wg[k].x * xx.x + wg[k].y * xx.y + wg[k].z * xx.z + wg[k].w * xx.w;
        au += wu[k].x * xx.x + wu[k].y * xx.y + wu[k].z * xx.z + wu[k].w * xx.w;
    }
#pragma unroll
    for (int o = 32; o > 0; o >>= 1) {
        ag += __shfl_down(ag, o, 64);
        au += __shfl_down(au, o, 64);
    }
    if (lane == 0) {
        float g = ag;
        float tt = tanhf(0.7978845608028654f * (g + 0.044715f * g * g * g));
        gu[row] = 0.5f * g * (1.f + tt) * au;
    }
}

// ---- Wd: wave per row over full 10240-col row, gu staged in 40 KB LDS ----
__global__ __launch_bounds__(256) void k_wd_nt(const float* __restrict__ Wd,
                                               const float* __restrict__ gu,
                                               float* __restrict__ ffn) {
    __shared__ f4 xs[2560];  // 40 KB
    int t = threadIdx.x;
    for (int i = t; i < 2560; i += 256) xs[i] = ((const f4*)gu)[i];
    __syncthreads();
    int lane = t & 63;
    int row = blockIdx.x * 4 + (t >> 6);
    const f4* Wr = (const f4*)Wd + (size_t)row * 2560 + lane;
    float acc = 0.f;
#pragma unroll
    for (int g = 0; g < 4; g++) {
        f4 wv[10];
#pragma unroll
        for (int k = 0; k < 10; k++)
            wv[k] = __builtin_nontemporal_load(Wr + (g * 10 + k) * 64);
#pragma unroll
        for (int k = 0; k < 10; k++) {
            f4 xx = xs[lane + (g * 10 + k) * 64];
            acc += wv[k].x * xx.x + wv[k].y * xx.y + wv[k].z * xx.z + wv[k].w * xx.w;
        }
    }
    acc = wave_red_sum(acc);
    if (lane == 0) ffn[row] = acc;
}

// out1 = (res?) res + rms(a)*(1+w1);  optionally out2 = rms(out1)*(1+w2)
__global__ void k_res_rms(const float* __restrict__ res,
                          const float* __restrict__ a,
                          const float* __restrict__ w1, float* __restrict__ out1,
                          const float* __restrict__ w2, float* __restrict__ out2) {
    const int K = D_ / 256;
    int t = threadIdx.x;
    float va[K];
    float ss = 0.f;
#pragma unroll
    for (int k = 0; k < K; k++) {
        int i = t + k * 256;
        va[k] = a[i];
        ss += va[k] * va[k];
    }
    float tot = block_red_sum(ss);
    float rs = rsqrtf(tot / (float)D_ + EPSF);
    float vo[K];
    float ss2 = 0.f;
#pragma unroll
    for (int k = 0; k < K; k++) {
        int i = t + k * 256;
        float r = res ? res[i] : 0.f;
        vo[k] = r + va[k] * rs * (1.f + w1[i]);
        out1[i] = vo[k];
        ss2 += vo[k] * vo[k];
    }
    if (out2) {
        float tot2 = block_red_sum(ss2);
        float rs2 = rsqrtf(tot2 / (float)D_ + EPSF);
#pragma unroll
        for (int k = 0; k < K; k++) {
            int i = t + k * 256;
            out2[i] = vo[k] * rs2 * (1.f + w2[i]);
        }
    }
}

__global__ void k_qnorm_rope(const float* __restrict__ qraw,
                             const float* __restrict__ cosv,
                             const float* __restrict__ sinv,
                             float* __restrict__ qout) {
    __shared__ float qn[HD_];
    int h = blockIdx.x, d = threadIdx.x;
    float v = qraw[h * HD_ + d];
    float tot = block_red_sum(v * v);
    float rs = rsqrtf(tot / (float)HD_ + EPSF);
    float n = v * rs;
    qn[d] = n;
    __syncthreads();
    float rot = (d < HD_ / 2) ? -qn[d + HD_ / 2] : qn[d - HD_ / 2];
    qout[h * HD_ + d] = n * cosv[d] + rot * sinv[d];
}

// scores: grid=(NKV_, SCH), block=256.  32 rows/block, 8 rows/wave,
// all 8 K-row loads issued before the reduce trees.
__global__ __launch_bounds__(256) void k_scores(const float* __restrict__ Kc,
                                                const float* __restrict__ q,
                                                const float* __restrict__ mask,
                                                float* __restrict__ s) {
    int kvh = blockIdx.x, chunk = blockIdx.y;
    int lane = threadIdx.x & 63, w = threadIdx.x >> 6;
    int h0 = 2 * kvh, h1 = h0 + 1;
    const f4* q4 = (const f4*)q;
    f4 q0 = q4[h0 * 64 + lane];
    f4 q1 = q4[h1 * 64 + lane];
    int lbase = chunk * (CTX_ / SCH) + w * 8;
    const f4* Kb = (const f4*)(Kc + ((size_t)kvh * CTX_ + lbase) * HD_) + lane;
    f4 kk[8];
#pragma unroll
    for (int i = 0; i < 8; i++) kk[i] = Kb[i * 64];
    float d0[8], d1[8];
#pragma unroll
    for (int i = 0; i < 8; i++) {
        d0[i] = kk[i].x * q0.x + kk[i].y * q0.y + kk[i].z * q0.z + kk[i].w * q0.w;
        d1[i] = kk[i].x * q1.x + kk[i].y * q1.y + kk[i].z * q1.z + kk[i].w * q1.w;
    }
#pragma unroll
    for (int o = 32; o > 0; o >>= 1) {
#pragma unroll
        for (int i = 0; i < 8; i++) {
            d0[i] += __shfl_down(d0[i], o, 64);
            d1[i] += __shfl_down(d1[i], o, 64);
        }
    }
    if (lane == 0) {
#pragma unroll
        for (int i = 0; i < 8; i++) {
            int l = lbase + i;
            float m = mask[l];
            s[(size_t)h0 * CTX_ + l] = d0[i] + m;
            s[(size_t)h1 * CTX_ + l] = d1[i] + m;
        }
    }
}

__global__ void k_softmax(float* __restrict__ s) {
    int h = blockIdx.x, t = threadIdx.x;
    float* sh = s + (size_t)h * CTX_;
    float m = -1e30f;
    for (int l = t; l < CTX_; l += 256) m = fmaxf(m, sh[l]);
    m = block_red_max(m);
    float sum = 0.f;
    for (int l = t; l < CTX_; l += 256) {
        float e = expf(sh[l] - m);
        sh[l] = e;
        sum += e;
    }
    sum = block_red_sum(sum);
    float inv = 1.f / sum;
    for (int l = t; l < CTX_; l += 256) sh[l] *= inv;
}

// wv: grid=(NKV_, WCH), block=256 (thread = d).  64 rows/chunk, streaming.
__global__ __launch_bounds__(256) void k_wv(const float* __restrict__ V,
                                            const float* __restrict__ p,
                                            float* __restrict__ part) {
    int kvh = blockIdx.x, chunk = blockIdx.y, d = threadIdx.x;
    int h0 = 2 * kvh, h1 = h0 + 1;
    constexpr int R = CTX_ / WCH;   // 64 rows
    __shared__ float p0[R], p1[R];
    int l0 = chunk * R;
    if (d < R) p0[d] = p[(size_t)h0 * CTX_ + l0 + d];
    else if (d < 2 * R) p1[d - R] = p[(size_t)h1 * CTX_ + l0 + d - R];
    __syncthreads();
    const float* Vb = V + ((size_t)kvh * CTX_ + l0) * HD_;
    float a0 = 0.f, a1 = 0.f;
#pragma unroll 8
    for (int li = 0; li < R; li++) {
        float v = Vb[(size_t)li * HD_ + d];
        a0 += p0[li] * v;
        a1 += p1[li] * v;
    }
    part[((h0 * WCH) + chunk) * HD_ + d] = a0;
    part[((h1 * WCH) + chunk) * HD_ + d] = a1;
}

__global__ void k_reduce_a(const float* __restrict__ part, float* __restrict__ a) {
    int h = blockIdx.x, d = threadIdx.x;
    float s = 0.f;
#pragma unroll
    for (int c = 0; c < WCH; c++) s += part[((h * WCH) + c) * HD_ + d];
    a[h * HD_ + d] = s;
}

extern "C" void kernel_launch(void* const* d_in, const int* in_sizes, int n_in,
                              void* d_out, int out_size, void* d_ws, size_t ws_size,
                              hipStream_t stream) {
    const float* x     = (const float*)d_in[0];
    const float* cosv  = (const float*)d_in[1];
    const float* sinv  = (const float*)d_in[2];
    const float* mask  = (const float*)d_in[3];
    const float* cK    = (const float*)d_in[4];
    const float* cV    = (const float*)d_in[5];
    const float* w_in  = (const float*)d_in[7];
    const float* w_pa  = (const float*)d_in[8];
    const float* w_pf  = (const float*)d_in[9];
    const float* w_pff = (const float*)d_in[10];
    const float* Wq    = (const float*)d_in[11];
    const float* Wo    = (const float*)d_in[12];
    const float* Wg    = (const float*)d_in[13];
    const float* Wu    = (const float*)d_in[14];
    const float* Wd    = (const float*)d_in[15];

    float* ws   = (float*)d_ws;
    float* h    = ws;             // 2560
    float* qraw = ws + 2560;      // 2048
    float* q    = ws + 4608;      // 2048
    float* sc   = ws + 6656;      // 32768
    float* pwv  = ws + 39424;     // 8*64*256 = 131072
    float* a    = ws + 170496;    // 2048
    float* ao   = ws + 172544;    // 2560
    float* x2   = ws + 175104;    // 2560
    float* h2   = ws + 177664;    // 2560
    float* gu   = ws + 180224;    // 10240
    float* ffn  = ws + 190464;    // 2560
    float* out  = (float*)d_out;

    // h = rmsnorm(x, w_in)
    k_res_rms<<<1, 256, 0, stream>>>(nullptr, x, w_in, h, nullptr, nullptr);
    // qraw = h @ Wq.T
    k_gemv_nt<D_><<<QD_ / 4, 256, 0, stream>>>(Wq, h, qraw);
    k_qnorm_rope<<<NH_, HD_, 0, stream>>>(qraw, cosv, sinv, q);
    // attention
    k_scores<<<dim3(NKV_, SCH), 256, 0, stream>>>(cK, q, mask, sc);
    k_softmax<<<NH_, 256, 0, stream>>>(sc);
    k_wv<<<dim3(NKV_, WCH), 256, 0, stream>>>(cV, sc, pwv);
    k_reduce_a<<<NH_, HD_, 0, stream>>>(pwv, a);
    // ao = a @ Wo.T
    k_gemv_nt<QD_><<<D_ / 4, 256, 0, stream>>>(Wo, a, ao);
    k_res_rms<<<1, 256, 0, stream>>>(x, ao, w_pa, x2, w_pf, h2);
    // gu = gelu(h2@Wg.T) * (h2@Wu.T)
    k_geglu_nt<<<FFN_ / 4, 256, 0, stream>>>(Wg, Wu, h2, gu);
    // ffn = gu @ Wd.T
    k_wd_nt<<<D_ / 4, 256, 0, stream>>>(Wd, gu, ffn);
    // out = x2 + rms(ffn)*(1+w_pff)
    k_res_rms<<<1, 256, 0, stream>>>(x2, ffn, w_pff, out, nullptr, nullptr);
}